// Round 1
// baseline (140.307 us; speedup 1.0000x reference)
//
#include <hip/hip_runtime.h>
#include <math.h>

// Problem constants: B=512, Q=100, C=81, V=117
#define Bn 512
#define Qn 100
#define Cn 81
#define Vn 117
#define NQ (Bn * Qn)            // 51200

// d_out layout (floats), outputs concatenated flat in return order:
// hoi_scores (B,Q,V) | obj_labels (B,Q) | sub_boxes (B,Q,4) | obj_boxes (B,Q,4) | keep (B,Q)
#define OFF_HOI  0
#define OFF_LAB  (NQ * Vn)
#define OFF_SUB  (OFF_LAB + NQ)
#define OFF_OBJ  (OFF_SUB + NQ * 4)
#define OFF_KEEP (OFF_OBJ + NQ * 4)

__device__ __forceinline__ float frcp(float x) { return __builtin_amdgcn_rcpf(x); }

// Single fused kernel: one block per image (256 thr = 4 waves).
// Phase 1: 7 passes x 16 items: softmax/argmax + sigmoid*mask + hoi writeback
//          (max_scores, labels, scaled boxes kept in LDS).
// Phase 2: stable rank sort (LDS).
// Phase 3: suppression-matrix rows via ballot (wave-pairs split rows).
// Phase 4: serial greedy chain + keep scatter.
__global__ __launch_bounds__(256) void hoi_fused(
    const float* __restrict__ obj_logits,
    const float* __restrict__ verb_logits,
    const float* __restrict__ sub_boxes,
    const float* __restrict__ obj_boxes,
    const float* __restrict__ cm,           // correct_mat, natural (V x C) layout
    const int*   __restrict__ target_sizes,
    float* __restrict__ out)
{
    __shared__ float CM[Vn * Cn];           // 37908 B, cm[v*81 + c]
    __shared__ float L[16 * Cn];            // 5184 B
    __shared__ float W[16 * Vn];            // 7488 B
    __shared__ float sc[Qn];                // max_scores
    __shared__ int   labs[Qn];
    __shared__ float4 Bsub[Qn], Bobj[Qn];   // scaled xyxy boxes (unsorted)
    __shared__ float4 Ssub[Qn], Sobj[Qn], Smeta[Qn];  // sorted; meta={sarea,oarea,lab,orig}
    __shared__ unsigned long long RR[2 * Qn];         // suppression rows (0..98 used)

    const int tid = threadIdx.x;
    const int b   = blockIdx.x;
    const int t   = tid & 15;               // lane within 16-lane group
    const int g   = tid >> 4;               // group 0..15

    // ---- stage correct_mat into LDS (coalesced float4 + 1-float tail) ----
    {
        const float4* c4 = (const float4*)cm;
        float4* C4 = (float4*)CM;
        for (int i = tid; i < (Vn * Cn) / 4; i += 256) C4[i] = c4[i];   // 2369 f4
        if (tid == 0) CM[Vn * Cn - 1] = cm[Vn * Cn - 1];
    }

    const float ih = (float)target_sizes[2 * b + 0];
    const float iw = (float)target_sizes[2 * b + 1];

    // ---- boxes: one thread per query, both boxes; write out + keep in LDS ----
    if (tid < Qn) {
        const int idx = b * Qn + tid;
        float4 bx = ((const float4*)sub_boxes)[idx];
        float4 r;
        r.x = (bx.x - 0.5f * bx.z) * iw;
        r.y = (bx.y - 0.5f * bx.w) * ih;
        r.z = (bx.x + 0.5f * bx.z) * iw;
        r.w = (bx.y + 0.5f * bx.w) * ih;
        ((float4*)(out + OFF_SUB))[idx] = r;
        Bsub[tid] = r;
        bx = ((const float4*)obj_boxes)[idx];
        r.x = (bx.x - 0.5f * bx.z) * iw;
        r.y = (bx.y - 0.5f * bx.w) * ih;
        r.z = (bx.x + 0.5f * bx.z) * iw;
        r.w = (bx.y + 0.5f * bx.w) * ih;
        ((float4*)(out + OFF_OBJ))[idx] = r;
        Bobj[tid] = r;
    }

    // ---- phase 1: 7 passes of 16 items (last pass: 4 items = exactly wave 0) ----
    for (int p = 0; p < 7; p++) {
        const int q0  = p * 16;
        const int cnt = (q0 + 16 <= Qn) ? 16 : (Qn - q0);   // 16,...,16,4

        {   // stage slabs, block-coalesced float4 (no OOB: bounded by cnt)
            const float4* lgs = (const float4*)(obj_logits + ((size_t)b * Qn + q0) * Cn);
            float4* Lv = (float4*)L;
            const int nL = cnt * Cn / 4;                    // 324 or 81
            for (int i = tid; i < nL; i += 256) Lv[i] = lgs[i];
            const float4* vls = (const float4*)(verb_logits + ((size_t)b * Qn + q0) * Vn);
            float4* Wv = (float4*)W;
            const int nW = cnt * Vn / 4;                    // 468 or 117
            for (int i = tid; i < nW; i += 256) Wv[i] = vls[i];
        }
        __syncthreads();

        if (g < cnt) {                      // whole waves active (cnt = 16 or 4)
            const int q   = q0 + g;
            const int idx = b * Qn + q;

            // obj softmax from LDS: cols 0..79 in 5 chunks, col 80 broadcast
            const float* lg = L + g * Cn;
            float l0 = lg[t], l1 = lg[t + 16], l2 = lg[t + 32], l3 = lg[t + 48], l4 = lg[t + 64];
            float l5 = lg[80];

            // argmax over cols [0,80): keep lowest col on tie
            float v = l0; int vid = t;
            if (l1 > v) { v = l1; vid = t + 16; }
            if (l2 > v) { v = l2; vid = t + 32; }
            if (l3 > v) { v = l3; vid = t + 48; }
            if (l4 > v) { v = l4; vid = t + 64; }
            #pragma unroll
            for (int o = 8; o; o >>= 1) {
                float ov = __shfl_xor(v, o, 64);
                int   oi = __shfl_xor(vid, o, 64);
                if (ov > v || (ov == v && oi < vid)) { v = ov; vid = oi; }
            }

            // sum(exp) over all 81 (logits ~N(0,1), exp safe)
            float e = __expf(l0) + __expf(l1) + __expf(l2) + __expf(l3) + __expf(l4);
            #pragma unroll
            for (int o = 8; o; o >>= 1) e += __shfl_xor(e, o, 64);
            e += __expf(l5);

            const int   label     = vid;    // group-uniform after reduction
            const float obj_score = __expf(v) * frcp(e);

            // verb sigmoid * obj_score * mask; write back into LDS slab
            float* vrow = W + g * Vn;
            float mx = 0.f;
            #pragma unroll
            for (int c = 0; c < 8; c++) {   // chunks 0..6 full, 7 partial (t<5)
                int col = t + 16 * c;
                if (col < Vn) {
                    float x = vrow[col];
                    float h = frcp(1.f + __expf(-x)) * obj_score * CM[col * Cn + label];
                    vrow[col] = h;
                    mx = fmaxf(mx, h);
                }
            }
            #pragma unroll
            for (int o = 8; o; o >>= 1) mx = fmaxf(mx, __shfl_xor(mx, o, 64));

            if (t == 0) {
                out[OFF_LAB + idx] = (float)label;
                sc[q]   = mx;
                labs[q] = label;
            }
        }
        __syncthreads();

        {   // store hoi slab, block-coalesced float4
            const float4* Wv = (const float4*)W;
            float4* ho = (float4*)(out + OFF_HOI + ((size_t)b * Qn + q0) * Vn);
            const int nW = cnt * Vn / 4;
            for (int i = tid; i < nW; i += 256) ho[i] = Wv[i];
        }
        __syncthreads();
    }

    // ---- phase 2: stable rank sort into Ssub/Sobj/Smeta ----
    if (tid < Qn) {
        const float kv = sc[tid];
        int r = 0;
        #pragma unroll 4
        for (int j = 0; j < Qn; j++) {
            float sj = sc[j];
            r += (sj > kv) || (sj == kv && j < tid);
        }
        float4 sb = Bsub[tid], ob = Bobj[tid];
        Ssub[r] = sb;
        Sobj[r] = ob;
        Smeta[r] = make_float4((sb.z - sb.x + 1.f) * (sb.w - sb.y + 1.f),
                               (ob.z - ob.x + 1.f) * (ob.w - ob.y + 1.f),
                               (float)labs[tid], (float)tid);
    }
    __syncthreads();

    // ---- phase 3: suppression rows; waves {0,1} rows 0..49, {2,3} rows 50..98 ----
    {
        const int tc   = tid & 127;         // sorted column j
        const int half = tid >> 7;
        const int lane = tid & 63;
        const int sub  = (tid >> 6) & 1;    // which 64-bit word of the row
        const bool jv  = (tc < Qn);

        float4 js = make_float4(0.f, 0.f, 0.f, 0.f), jo = js, jm = js;
        if (jv) { js = Ssub[tc]; jo = Sobj[tc]; jm = Smeta[tc]; }

        const int i0 = half ? 50 : 0;
        const int i1 = half ? (Qn - 1) : 50;
        for (int i = i0; i < i1; i++) {
            float4 is = Ssub[i], io = Sobj[i], im = Smeta[i];   // uniform -> broadcast
            float ww = fmaxf(0.f, fminf(is.z, js.z) - fmaxf(is.x, js.x) + 1.f);
            float hh = fmaxf(0.f, fminf(is.w, js.w) - fmaxf(is.y, js.y) + 1.f);
            float inter = ww * hh;
            float iou_s = inter / (im.x + jm.x - inter);
            ww = fmaxf(0.f, fminf(io.z, jo.z) - fmaxf(io.x, jo.x) + 1.f);
            hh = fmaxf(0.f, fminf(io.w, jo.w) - fmaxf(io.y, jo.y) + 1.f);
            inter = ww * hh;
            float iou_o = inter / (im.y + jm.y - inter);
            bool cond = jv && (tc > i) && (jm.z == im.z) && (iou_s * sqrtf(iou_o) > 0.7f);
            unsigned long long m = __ballot(cond);
            if (lane == 0) RR[2 * i + sub] = m;
        }
    }
    __syncthreads();

    // ---- phase 4: serial greedy chain (wave 0, redundant per-lane) + scatter ----
    if (tid < 64) {
        unsigned long long s0 = 0ull, s1 = 0ull;
        for (int k = 0; k < Qn - 1; k++) {
            unsigned long long dead = ((k < 64 ? s0 : s1) >> (k & 63)) & 1ull;
            if (!dead) { s0 |= RR[2 * k]; s1 |= RR[2 * k + 1]; }
        }
        float* keepp = out + OFF_KEEP + (size_t)b * Qn;
        keepp[(int)Smeta[tid].w] = ((s0 >> tid) & 1ull) ? 0.f : 1.f;
        if (tid < 36)
            keepp[(int)Smeta[64 + tid].w] = ((s1 >> tid) & 1ull) ? 0.f : 1.f;
    }
}

extern "C" void kernel_launch(void* const* d_in, const int* in_sizes, int n_in,
                              void* d_out, int out_size, void* d_ws, size_t ws_size,
                              hipStream_t stream) {
    const float* obj_logits   = (const float*)d_in[0];
    const float* verb_logits  = (const float*)d_in[1];
    const float* sub_boxes    = (const float*)d_in[2];
    const float* obj_boxes    = (const float*)d_in[3];
    const float* correct_mat  = (const float*)d_in[4];
    const int*   target_sizes = (const int*)d_in[5];
    float* out = (float*)d_out;
    (void)d_ws; (void)ws_size; (void)in_sizes; (void)n_in; (void)out_size;

    hoi_fused<<<Bn, 256, 0, stream>>>(obj_logits, verb_logits, sub_boxes,
                                      obj_boxes, correct_mat, target_sizes, out);
}

// Round 2
// 119.784 us; speedup vs baseline: 1.1713x; 1.1713x over previous
//
#include <hip/hip_runtime.h>
#include <math.h>

// Problem constants: B=512, Q=100, C=81, V=117
#define Bn 512
#define Qn 100
#define Cn 81
#define Vn 117
#define NQ (Bn * Qn)            // 51200

// d_out layout (floats), outputs concatenated flat in return order:
// hoi_scores (B,Q,V) | obj_labels (B,Q) | sub_boxes (B,Q,4) | obj_boxes (B,Q,4) | keep (B,Q)
#define OFF_HOI  0
#define OFF_LAB  (NQ * Vn)
#define OFF_SUB  (OFF_LAB + NQ)
#define OFF_OBJ  (OFF_SUB + NQ * 4)
#define OFF_KEEP (OFF_OBJ + NQ * 4)

__device__ __forceinline__ float frcp(float x) { return __builtin_amdgcn_rcpf(x); }

// Single fused kernel, one block (512 thr = 8 waves) per image.
//  Phase 0: stage correct_mat into LDS; boxes (kept in registers).
//  Phase 1: BARRIER-FREE scoring: each 16-lane group owns a query, reads
//           obj/verb rows straight from global (64B segments), writes hoi
//           straight back. Only CM comes from LDS.
//  Phase 2: stable rank sort (boxes from registers -> sorted LDS, overlaying CM).
//  Phase 3: suppression rows via ballot, 4 x 128-thr units x ~25 rows.
//  Phase 4: serial greedy chain (prefetched) + keep scatter.
__global__ __launch_bounds__(512) void hoi_fused(
    const float* __restrict__ obj_logits,
    const float* __restrict__ verb_logits,
    const float* __restrict__ sub_boxes,
    const float* __restrict__ obj_boxes,
    const float* __restrict__ cm,           // correct_mat, natural (V x C) layout
    const int*   __restrict__ target_sizes,
    float* __restrict__ out)
{
    // Overlay: CM (37908 B, phase 1) shares LDS with the NMS arrays (6400 B,
    // phases 2-4). A barrier separates last CM read from first overlay write.
    __shared__ __align__(16) char smem[37920];
    __shared__ float sc[Qn];                // max_scores
    __shared__ int   labs[Qn];

    float*      CM    = (float*)smem;                   // [Vn*Cn]
    float4*     Ssub  = (float4*)smem;                  // [Qn]
    float4*     Sobj  = Ssub + Qn;                      // [Qn]
    float4*     Smeta = Sobj + Qn;                      // [Qn] {sarea,oarea,lab,orig}
    ulonglong2* RR    = (ulonglong2*)(Smeta + Qn);      // [Qn] suppression rows

    const int tid = threadIdx.x;
    const int b   = blockIdx.x;

    // ---- phase 0a: stage correct_mat into LDS (coalesced float4 + tail) ----
    {
        const float4* c4 = (const float4*)cm;
        float4* C4 = (float4*)CM;
        for (int i = tid; i < (Vn * Cn) / 4; i += 512) C4[i] = c4[i];   // 2369 f4
        if (tid == 0) CM[Vn * Cn - 1] = cm[Vn * Cn - 1];
    }

    // ---- phase 0b: boxes, one thread per query; results live in REGISTERS
    //      (rs, ro) until the sort. Also written to out. ----
    float4 rs = make_float4(0.f, 0.f, 0.f, 0.f), ro = rs;
    if (tid < Qn) {
        const float ih = (float)target_sizes[2 * b + 0];
        const float iw = (float)target_sizes[2 * b + 1];
        const int idx = b * Qn + tid;
        float4 bx = ((const float4*)sub_boxes)[idx];
        rs.x = (bx.x - 0.5f * bx.z) * iw;
        rs.y = (bx.y - 0.5f * bx.w) * ih;
        rs.z = (bx.x + 0.5f * bx.z) * iw;
        rs.w = (bx.y + 0.5f * bx.w) * ih;
        ((float4*)(out + OFF_SUB))[idx] = rs;
        bx = ((const float4*)obj_boxes)[idx];
        ro.x = (bx.x - 0.5f * bx.z) * iw;
        ro.y = (bx.y - 0.5f * bx.w) * ih;
        ro.z = (bx.x + 0.5f * bx.z) * iw;
        ro.w = (bx.y + 0.5f * bx.w) * ih;
        ((float4*)(out + OFF_OBJ))[idx] = ro;
    }
    __syncthreads();                        // CM ready

    // ---- phase 1: barrier-free scoring; group = 16 lanes, 32 groups ----
    {
        const int t = tid & 15;             // lane within group
        const int g = tid >> 4;             // group 0..31
        for (int q = g; q < Qn; q += 32) {
            const size_t idx = (size_t)b * Qn + q;
            const float* lg = obj_logits + idx * Cn;
            const float* vl = verb_logits + idx * Vn;

            // issue all independent global loads up front
            float l0 = lg[t], l1 = lg[t + 16], l2 = lg[t + 32],
                  l3 = lg[t + 48], l4 = lg[t + 64], l5 = lg[80];
            float w0 = vl[t], w1 = vl[t + 16], w2 = vl[t + 32], w3 = vl[t + 48],
                  w4 = vl[t + 64], w5 = vl[t + 80], w6 = vl[t + 96];
            float w7 = (t < 5) ? vl[112 + t] : 0.f;

            // argmax over cols [0,80): keep lowest col on tie
            float v = l0; int vid = t;
            if (l1 > v) { v = l1; vid = t + 16; }
            if (l2 > v) { v = l2; vid = t + 32; }
            if (l3 > v) { v = l3; vid = t + 48; }
            if (l4 > v) { v = l4; vid = t + 64; }
            #pragma unroll
            for (int o = 8; o; o >>= 1) {
                float ov = __shfl_xor(v, o, 64);
                int   oi = __shfl_xor(vid, o, 64);
                if (ov > v || (ov == v && oi < vid)) { v = ov; vid = oi; }
            }

            // sum(exp) over all 81 (logits ~N(0,1), exp safe)
            float e = __expf(l0) + __expf(l1) + __expf(l2) + __expf(l3) + __expf(l4);
            #pragma unroll
            for (int o = 8; o; o >>= 1) e += __shfl_xor(e, o, 64);
            e += __expf(l5);

            const int   label     = vid;    // group-uniform after reduction
            const float obj_score = __expf(v) * frcp(e);

            // verb sigmoid * obj_score * mask; store hoi direct from regs
            float* hout = out + OFF_HOI + idx * Vn;
            const float* cmrow = CM + label;            // CM[col*Cn + label]
            float mx = 0.f;
            {
                float h;
                h = frcp(1.f + __expf(-w0)) * obj_score * cmrow[(t      ) * Cn];
                hout[t      ] = h; mx = fmaxf(mx, h);
                h = frcp(1.f + __expf(-w1)) * obj_score * cmrow[(t +  16) * Cn];
                hout[t +  16] = h; mx = fmaxf(mx, h);
                h = frcp(1.f + __expf(-w2)) * obj_score * cmrow[(t +  32) * Cn];
                hout[t +  32] = h; mx = fmaxf(mx, h);
                h = frcp(1.f + __expf(-w3)) * obj_score * cmrow[(t +  48) * Cn];
                hout[t +  48] = h; mx = fmaxf(mx, h);
                h = frcp(1.f + __expf(-w4)) * obj_score * cmrow[(t +  64) * Cn];
                hout[t +  64] = h; mx = fmaxf(mx, h);
                h = frcp(1.f + __expf(-w5)) * obj_score * cmrow[(t +  80) * Cn];
                hout[t +  80] = h; mx = fmaxf(mx, h);
                h = frcp(1.f + __expf(-w6)) * obj_score * cmrow[(t +  96) * Cn];
                hout[t +  96] = h; mx = fmaxf(mx, h);
                if (t < 5) {
                    h = frcp(1.f + __expf(-w7)) * obj_score * cmrow[(112 + t) * Cn];
                    hout[112 + t] = h; mx = fmaxf(mx, h);
                }
            }
            #pragma unroll
            for (int o = 8; o; o >>= 1) mx = fmaxf(mx, __shfl_xor(mx, o, 64));

            if (t == 0) {
                out[OFF_LAB + idx] = (float)label;
                sc[q]   = mx;
                labs[q] = label;
            }
        }
    }
    __syncthreads();                        // sc/labs ready; CM dead -> overlay ok

    // ---- phase 2: stable rank sort into Ssub/Sobj/Smeta (boxes from regs) ----
    if (tid < Qn) {
        const float kv = sc[tid];
        int r = 0;
        #pragma unroll 4
        for (int j = 0; j < Qn; j++) {
            float sj = sc[j];
            r += (sj > kv) || (sj == kv && j < tid);
        }
        Ssub[r] = rs;
        Sobj[r] = ro;
        Smeta[r] = make_float4((rs.z - rs.x + 1.f) * (rs.w - rs.y + 1.f),
                               (ro.z - ro.x + 1.f) * (ro.w - ro.y + 1.f),
                               (float)labs[tid], (float)tid);
    }
    __syncthreads();

    // ---- phase 3: suppression rows; 4 units x 128 cols x ~25 rows ----
    {
        const int tc   = tid & 127;         // sorted column j
        const int uq   = tid >> 7;          // unit 0..3
        const int lane = tid & 63;
        const int sub  = (tid >> 6) & 1;    // which 64-bit word of the row
        const bool jv  = (tc < Qn);

        float4 js = make_float4(0.f, 0.f, 0.f, 0.f), jo = js, jm = js;
        if (jv) { js = Ssub[tc]; jo = Sobj[tc]; jm = Smeta[tc]; }

        const int i0 = 25 * uq;
        const int i1 = (25 * uq + 25 < Qn - 1) ? 25 * uq + 25 : Qn - 1;
        for (int i = i0; i < i1; i++) {
            float4 is = Ssub[i], io = Sobj[i], im = Smeta[i];   // uniform -> bcast
            float ww = fmaxf(0.f, fminf(is.z, js.z) - fmaxf(is.x, js.x) + 1.f);
            float hh = fmaxf(0.f, fminf(is.w, js.w) - fmaxf(is.y, js.y) + 1.f);
            float inter = ww * hh;
            float iou_s = inter / (im.x + jm.x - inter);
            ww = fmaxf(0.f, fminf(io.z, jo.z) - fmaxf(io.x, jo.x) + 1.f);
            hh = fmaxf(0.f, fminf(io.w, jo.w) - fmaxf(io.y, jo.y) + 1.f);
            inter = ww * hh;
            float iou_o = inter / (im.y + jm.y - inter);
            bool cond = jv && (tc > i) && (jm.z == im.z) && (iou_s * sqrtf(iou_o) > 0.7f);
            unsigned long long m = __ballot(cond);
            if (lane == 0) ((unsigned long long*)&RR[i])[sub] = m;
        }
    }
    __syncthreads();

    // ---- phase 4: serial greedy chain (wave 0, prefetched) + scatter ----
    if (tid < 64) {
        unsigned long long s0 = 0ull, s1 = 0ull;
        ulonglong2 r = RR[0];
        for (int k = 0; k < Qn - 1; k++) {
            ulonglong2 rn = RR[(k + 1 < Qn - 1) ? k + 1 : k];   // prefetch next
            unsigned long long dead = ((k < 64 ? s0 : s1) >> (k & 63)) & 1ull;
            if (!dead) { s0 |= r.x; s1 |= r.y; }
            r = rn;
        }
        float* keepp = out + OFF_KEEP + (size_t)b * Qn;
        keepp[(int)Smeta[tid].w] = ((s0 >> tid) & 1ull) ? 0.f : 1.f;
        if (tid < 36)
            keepp[(int)Smeta[64 + tid].w] = ((s1 >> tid) & 1ull) ? 0.f : 1.f;
    }
}

extern "C" void kernel_launch(void* const* d_in, const int* in_sizes, int n_in,
                              void* d_out, int out_size, void* d_ws, size_t ws_size,
                              hipStream_t stream) {
    const float* obj_logits   = (const float*)d_in[0];
    const float* verb_logits  = (const float*)d_in[1];
    const float* sub_boxes    = (const float*)d_in[2];
    const float* obj_boxes    = (const float*)d_in[3];
    const float* correct_mat  = (const float*)d_in[4];
    const int*   target_sizes = (const int*)d_in[5];
    float* out = (float*)d_out;
    (void)d_ws; (void)ws_size; (void)in_sizes; (void)n_in; (void)out_size;

    hoi_fused<<<Bn, 512, 0, stream>>>(obj_logits, verb_logits, sub_boxes,
                                      obj_boxes, correct_mat, target_sizes, out);
}